// Round 4
// baseline (150.882 us; speedup 1.0000x reference)
//
#include <hip/hip_runtime.h>
#include <stdint.h>

#define HID 128
#define BPB 16  // batch elements (waves) per block; block = 1024 threads

typedef float v2f __attribute__((ext_vector_type(2)));

// Full-wave64 f32 sum via DPP (VALU pipe, no LDS). Totals land in lane 63.
__device__ __forceinline__ void wave_reduce_add2(float& a, float& b) {
  asm("v_add_f32 %0, %0, %0 row_shr:1 bound_ctrl:0\n\t"
      "v_add_f32 %1, %1, %1 row_shr:1 bound_ctrl:0\n\t"
      "v_add_f32 %0, %0, %0 row_shr:2 bound_ctrl:0\n\t"
      "v_add_f32 %1, %1, %1 row_shr:2 bound_ctrl:0\n\t"
      "v_add_f32 %0, %0, %0 row_shr:4 bound_ctrl:0\n\t"
      "v_add_f32 %1, %1, %1 row_shr:4 bound_ctrl:0\n\t"
      "v_add_f32 %0, %0, %0 row_shr:8 bound_ctrl:0\n\t"
      "v_add_f32 %1, %1, %1 row_shr:8 bound_ctrl:0\n\t"
      "v_add_f32 %0, %0, %0 row_bcast:15 row_mask:0xa\n\t"
      "v_add_f32 %1, %1, %1 row_bcast:15 row_mask:0xa\n\t"
      "v_add_f32 %0, %0, %0 row_bcast:31 row_mask:0xc\n\t"
      "v_add_f32 %1, %1, %1 row_bcast:31 row_mask:0xc\n\t"
      : "+v"(a), "+v"(b));
}

__global__ __launch_bounds__(1024, 4) void lsnn_fwd(
    const float* __restrict__ x,      // (B,4)
    const float* __restrict__ w_in,   // (128,8)
    const float* __restrict__ w_rec,  // (128,128)
    const float* __restrict__ w_out,  // (2,128)
    float* __restrict__ out,          // (B,2)
    int B)
{
#pragma clang fp contract(off)
  // Transposed recurrent weights, plain layout: wt[k][l] = (w_rec[l][k],
  // w_rec[l+64][k]). Per spiking k (wave-uniform scalar), lanes read 512
  // contiguous bytes -> conflict-free ds_read_b64, no address swizzle.
  __shared__ float2 wt[HID * 64];

  const int tid = threadIdx.x;
#pragma unroll
  for (int m = 0; m < 8; ++m) {
    int idx = m * 1024 + tid;
    int l = idx & 63;   // lane-fast -> contiguous LDS stores (conflict-free)
    int k = idx >> 6;   // 0..127 presynaptic
    wt[(k << 6) | l] = make_float2(w_rec[l * HID + k], w_rec[(l + 64) * HID + k]);
  }
  __syncthreads();

  const int lane = tid & 63;
  const int b = blockIdx.x * BPB + (tid >> 6);
  if (b >= B) return;

  const int j0 = lane;
  const int j1 = lane + 64;
  const v2f zero2 = {0.0f, 0.0f};

  // ---------- encoder: 4 effective channels (pos/neg mutually exclusive) ---
  float cc[4], ev[4];
  v2f wsel[4];
  {
#pragma unroll
    for (int c = 0; c < 4; ++c) {
      float p = 50.0f * x[b * 4 + c];
      cc[c] = fabsf(p);
      ev[c] = 0.0f;
      int col = (p > 0.0f) ? c : (c + 4);
      wsel[c].x = w_in[j0 * 8 + col];
      wsel[c].y = w_in[j1 * 8 + col];
    }
  }

  uint64_t pk[5];  // 40 steps x 4 channel-bits, one byte per step
#pragma unroll
  for (int tw = 0; tw < 5; ++tw) {
    uint64_t pw = 0;
    for (int ts = 0; ts < 8; ++ts) {
      unsigned byte = 0;
#pragma unroll
      for (int c = 0; c < 4; ++c) {
        ev[c] = ev[c] + 0.1f * (cc[c] - ev[c]);
        if (ev[c] - 1.0f > 0.0f) {
          byte |= (1u << c);
          ev[c] = 0.0f;
        }
      }
      pw |= ((uint64_t)byte) << (ts << 3);
    }
    pk[tw] = pw;
  }

  v2f wop0, wop1;  // (w_out[0][j0], w_out[1][j0]) and (w_out[0][j1], w_out[1][j1])
  wop0.x = w_out[j0];       wop0.y = w_out[HID + j0];
  wop1.x = w_out[j1];       wop1.y = w_out[HID + j1];

  // ---------- state (packed pairs) ----------
  v2f vv = zero2, ii = zero2, io = zero2, vo = zero2;
  v2f bb = {1.0f, 1.0f};
  v2f mm = {-INFINITY, -INFINITY};
  uint64_t zm0 = 0ull, zm1 = 0ull;

  const char* wtb = (const char*)wt;
  const int vb = lane << 3;  // per-lane float2 byte base within a k-row

  // ---------- T=40 recurrent steps (5 words x 8 steps, static pk index) ----
#pragma unroll
  for (int tw = 0; tw < 5; ++tw) {
    uint64_t pw = pk[tw];
    for (int ts = 0; ts < 8; ++ts) {
      v2f vd = vv + 0.1f * (ii - vv);
      v2f id = ii - 0.2f * ii;
      v2f one_minus_b = {1.0f - bb.x, 1.0f - bb.y};
      v2f bd = bb + 1.4285714285714286e-06f * one_minus_b;
      bool z0 = (vd.x - bd.x) > 0.0f;
      bool z1 = (vd.y - bd.y) > 0.0f;
      uint64_t nz0 = __ballot(z0);
      uint64_t nz1 = __ballot(z1);
      vv.x = z0 ? 0.0f : vd.x;
      vv.y = z1 ? 0.0f : vd.y;
      bb.x = bd.x + (z0 ? 0.0025714285714285714f : 0.0f);
      bb.y = bd.y + (z1 ? 0.0025714285714285714f : 0.0f);

      // readout projection of z_new: DPP wave-reduce (valid in lane 63 only)
      v2f pp = (z0 ? wop0 : zero2) + (z1 ? wop1 : zero2);
      float p0 = pp.x, p1 = pp.y;
      wave_reduce_add2(p0, p1);

      // LI readout (vo uses OLD io), running max — valid in lane 63 only
      v2f von = vo + 0.1f * (io - vo);
      v2f pv; pv.x = p0; pv.y = p1;
      io = (io - 0.2f * io) + pv;
      vo = von;
      mm.x = fmaxf(mm.x, von.x);
      mm.y = fmaxf(mm.y, von.y);

      // input current from encoder spikes (wave-uniform -> scalar branches)
      int xb = __builtin_amdgcn_readfirstlane((int)((pw >> (ts << 3)) & 0xFF));
      v2f ai = zero2;
      if (xb & 1) ai += wsel[0];
      if (xb & 2) ai += wsel[1];
      if (xb & 4) ai += wsel[2];
      if (xb & 8) ai += wsel[3];

      // recurrent current from OLD z: one conflict-free ds_read_b64 +
      // one v_pk_add_f32 per spiking k; 32-bit mask words, ascending k
      // (reference accumulation order preserved)
      v2f ar = zero2;
      {
        uint32_t m0 = (uint32_t)zm0;
        while (m0) {
          int k = __builtin_ctz(m0); m0 &= m0 - 1;
          ar += *(const v2f*)(wtb + ((k << 9) | vb));
        }
        uint32_t m1 = (uint32_t)(zm0 >> 32);
        while (m1) {
          int k = __builtin_ctz(m1); m1 &= m1 - 1;
          ar += *(const v2f*)(wtb + 16384 + ((k << 9) | vb));
        }
        uint32_t m2 = (uint32_t)zm1;
        while (m2) {
          int k = __builtin_ctz(m2); m2 &= m2 - 1;
          ar += *(const v2f*)(wtb + 32768 + ((k << 9) | vb));
        }
        uint32_t m3 = (uint32_t)(zm1 >> 32);
        while (m3) {
          int k = __builtin_ctz(m3); m3 &= m3 - 1;
          ar += *(const v2f*)(wtb + 49152 + ((k << 9) | vb));
        }
      }

      ii = (id + ai) + ar;

      zm0 = nz0;
      zm1 = nz1;
    }
  }

  // ---------- softmax over the 2 per-batch max-voltages (lane 63 valid) ----
  if (lane == 63) {
    float mx = fmaxf(mm.x, mm.y);
    float e0 = expf(mm.x - mx);
    float e1 = expf(mm.y - mx);
    float s = e0 + e1;
    out[b * 2 + 0] = e0 / s;
    out[b * 2 + 1] = e1 / s;
  }
}

extern "C" void kernel_launch(void* const* d_in, const int* in_sizes, int n_in,
                              void* d_out, int out_size, void* d_ws, size_t ws_size,
                              hipStream_t stream) {
  (void)n_in; (void)out_size; (void)d_ws; (void)ws_size;
  const float* x = (const float*)d_in[0];
  const float* w_in = (const float*)d_in[1];
  const float* w_rec = (const float*)d_in[2];
  const float* w_out = (const float*)d_in[3];
  float* out = (float*)d_out;
  int B = in_sizes[0] / 4;
  int blocks = (B + BPB - 1) / BPB;
  lsnn_fwd<<<blocks, 1024, 0, stream>>>(x, w_in, w_rec, w_out, out, B);
}